// Round 14
// baseline (123.152 us; speedup 1.0000x reference)
//
#include <hip/hip_runtime.h>
#include <hip/hip_bf16.h>

typedef unsigned short u16;
typedef unsigned int u32;
typedef unsigned char u8;
typedef __attribute__((ext_vector_type(4))) int i32x4;

#define MM 4096
#define NN 4096
#define KK 4096   // K in elements == bytes for int8

#define BAR __builtin_amdgcn_s_barrier()
#define FENCE asm volatile("" ::: "memory")
#define WAITVM(n) asm volatile("s_waitcnt vmcnt(" #n ")" ::: "memory")

// LDS (bytes): A only, double-buffered: A0 @0, A1 @16384. Total 32 KiB.
#define ABUF(sh, b) ((sh) + (b) * 16384)

// ---- merged conversion pass -----------------------------------------------
// blocks [0,4096):   W int32 -> packed int8 (16 i8/thread)
// blocks [4096,8192): A fp32 -> int8, per-row symmetric scale (1 row/block)
__global__ __launch_bounds__(256) void cvt_k(const int* __restrict__ w,
                                             u8* __restrict__ ow,
                                             const float* __restrict__ x,
                                             u8* __restrict__ oa,
                                             float* __restrict__ dA) {
  const int bid = blockIdx.x;
  const int t = threadIdx.x;
  if (bid < 4096) {
    int i = bid * 256 + t;
    const int4* w4 = (const int4*)w + (size_t)i * 4;
    i32x4 r;
#pragma unroll
    for (int j = 0; j < 4; ++j) {
      int4 v = w4[j];
      r[j] = (v.x & 255) | ((v.y & 255) << 8) | ((v.z & 255) << 16) |
             ((u32)(v.w & 255) << 24);
    }
    *(i32x4*)(ow + (size_t)i * 16) = r;
  } else {
    const int row = bid - 4096;
    const float4* xr = (const float4*)(x + (size_t)row * KK);
    float4 v[4];
    float mx = 0.f;
#pragma unroll
    for (int j = 0; j < 4; ++j) {
      v[j] = xr[t + j * 256];
      mx = fmaxf(mx, fmaxf(fmaxf(fabsf(v[j].x), fabsf(v[j].y)),
                           fmaxf(fabsf(v[j].z), fabsf(v[j].w))));
    }
#pragma unroll
    for (int off = 32; off; off >>= 1) mx = fmaxf(mx, __shfl_down(mx, off));
    __shared__ float sm[4];
    if ((t & 63) == 0) sm[t >> 6] = mx;
    __syncthreads();
    mx = fmaxf(fmaxf(sm[0], sm[1]), fmaxf(sm[2], sm[3]));
    mx = fmaxf(mx, 1e-20f);
    const float inv = 127.0f / mx;
    if (t == 0) dA[row] = mx / 127.0f;
    u32* orow = (u32*)(oa + (size_t)row * KK);
#pragma unroll
    for (int j = 0; j < 4; ++j) {
      int qx = (int)rintf(v[j].x * inv), qy = (int)rintf(v[j].y * inv);
      int qz = (int)rintf(v[j].z * inv), qw = (int)rintf(v[j].w * inv);
      orow[t + j * 256] =
          (qx & 255) | ((qy & 255) << 8) | ((qz & 255) << 16) | ((u32)(qw & 255) << 24);
    }
  }
}

// ---- async global->LDS, width 16 ------------------------------------------
__device__ __forceinline__ void gload16(const u8* g, u8* l) {
  __builtin_amdgcn_global_load_lds(
      (const __attribute__((address_space(1))) void*)g,
      (__attribute__((address_space(3))) void*)l, 16, 0, 0);
}

// Stage one A half-tile (128 rows x 64 B) = 8 KB; ONE gload16/thread (512T).
__device__ __forceinline__ void stage_half(const u8* __restrict__ gRowBase,
                                           int k0, u8* ldsHalf, int tid) {
  int row = tid >> 2;                        // 4 x16B chunks per 64B row
  int c = (tid & 3) ^ ((row >> 1) & 3);
  gload16(gRowBase + (size_t)row * KK + k0 + c * 16, ldsHalf + tid * 16);
}

// Swizzled read of one 16B i8 fragment at logical (row r, 16B-chunk q).
__device__ __forceinline__ i32x4 ldsfrag(const u8* base, int r, int q) {
  return *(const i32x4*)(base + r * 64 + (((q ^ (r >> 1)) & 3) << 4));
}

#define MFMAI8(a, b, c) __builtin_amdgcn_mfma_i32_16x16x64_i8(a, b, c, 0, 0, 0)

// ---- 256x256 tile, BK=64, A via LDS, B DIRECT TO REGISTERS (flatmm) --------
// Per-tile issue order: R1: B(t+1) 4x global_load_dwordx4 -> bN;
//                       R3: A(t+2) 2x global_load_lds.
// Steady queue: enter {B(t):4, A(t+1):2}; R1 +4 -> 10, WAITVM(6) drains B(t);
// R2-end WAITVM(4) drains A(t+1); single BAR (A(t) fully read + A(t+1)
// published); R3 +2 -> 6 entering t+1. Prologue: A(0),B(0),A(1) -> WAITVM(6).
// bC/bN alternate via x2-unrolled caller (static names).
template <int MODE>  // 0 = steady (t<=61), 1 = t==62, 2 = t==63
__device__ __forceinline__ void do_tile(
    int t, i32x4 (&acc)[8][4], const u8* Ag, const u8* Bg, u8* sh,
    int tid, int lr, int hi, int wr,
    i32x4 (&afr0)[4], i32x4 (&afr1)[4], i32x4 (&bC)[4], i32x4 (&bN)[4]) {
  const int b = t & 1;
  u8* Acur = ABUF(sh, b);
  u8* Anxt = ABUF(sh, b ^ 1);

  // ---- R1: issue B(t+1) -> bN; wait B(t); MFMA G1 = afr0 x bC01
  if (MODE <= 1) {
#pragma unroll
    for (int n = 0; n < 4; ++n)
      bN[n] = *(const i32x4*)(Bg + (size_t)n * (16 * KK) + (t + 1) * 64);
  }
  if (MODE <= 1) { WAITVM(6); } else { WAITVM(0); }
  __builtin_amdgcn_s_setprio(1);
#pragma unroll
  for (int m = 0; m < 4; ++m)
#pragma unroll
    for (int n = 0; n < 2; ++n)
      acc[m][n] = MFMAI8(afr0[m], bC[n], acc[m][n]);
  __builtin_amdgcn_s_setprio(0);

  // ---- R2: read afr1(t); MFMA G2 = afr0 x bC23; publish A(t+1)
#pragma unroll
  for (int m = 0; m < 4; ++m)
    afr1[m] = ldsfrag(Acur, wr * 128 + 64 + m * 16 + lr, hi);
  __builtin_amdgcn_s_setprio(1);
#pragma unroll
  for (int m = 0; m < 4; ++m)
#pragma unroll
    for (int n = 0; n < 2; ++n)
      acc[m][2 + n] = MFMAI8(afr0[m], bC[2 + n], acc[m][2 + n]);
  __builtin_amdgcn_s_setprio(0);
  if (MODE <= 1) {
    WAITVM(4);   // own A(t+1) stages landed
    FENCE; BAR;  // all waves: A(t) fully read + A(t+1) published
  }

  // ---- R3: stage A(t+2) -> Acur; read afr0(t+1); MFMA G3 = afr1 x bC01
  if (MODE == 0) {
    stage_half(Ag,            (t + 2) * 64, Acur,        tid);
    stage_half(Ag + 128 * KK, (t + 2) * 64, Acur + 8192, tid);
  }
  if (MODE <= 1) {
#pragma unroll
    for (int m = 0; m < 4; ++m)
      afr0[m] = ldsfrag(Anxt, wr * 128 + m * 16 + lr, hi);
  }
  __builtin_amdgcn_s_setprio(1);
#pragma unroll
  for (int m = 0; m < 4; ++m)
#pragma unroll
    for (int n = 0; n < 2; ++n)
      acc[4 + m][n] = MFMAI8(afr1[m], bC[n], acc[4 + m][n]);
  __builtin_amdgcn_s_setprio(0);

  // ---- R4: MFMA G4 = afr1 x bC23
  __builtin_amdgcn_s_setprio(1);
#pragma unroll
  for (int m = 0; m < 4; ++m)
#pragma unroll
    for (int n = 0; n < 2; ++n)
      acc[4 + m][2 + n] = MFMAI8(afr1[m], bC[2 + n], acc[4 + m][2 + n]);
  __builtin_amdgcn_s_setprio(0);
}

__global__ __launch_bounds__(512, 2) void gemm_k(const u8* __restrict__ A,
                                                 const u8* __restrict__ W,
                                                 const float* __restrict__ dA,
                                                 const float* __restrict__ scales,
                                                 const float* __restrict__ bias,
                                                 float* __restrict__ out) {
  __shared__ u8 sh[32768];  // 32 KiB: A double-buffer only

  // T1: XCD-aware swizzle (nwg = 256)
  const int cpx = gridDim.x >> 3;
  const int wg = (blockIdx.x & 7) * cpx + (blockIdx.x >> 3);
  const int bm = wg >> 4;
  const int bn = wg & 15;

  const int tid = threadIdx.x;
  const int lane = tid & 63;
  const int lr = lane & 15;
  const int hi = lane >> 4;
  const int wid = tid >> 6;
  const int wr = wid >> 2;  // 2 (M) x 4 (N) wave grid; wave tile 128x64
  const int wc = wid & 3;

  i32x4 acc[8][4] = {};
  i32x4 afr0[4], afr1[4], bE[4], bO[4];

  const u8* Ag = A + (size_t)bm * 256 * KK;
  // per-lane B base: row = bn*256 + wc*64 + lr, byte offset hi*16 within K-window
  const u8* Bg = W + ((size_t)(bn * 256 + wc * 64 + lr)) * KK + hi * 16;

  // ---- prologue (issue order matters for vmcnt): A(0):2, B(0):4, A(1):2
  stage_half(Ag,             0, ABUF(sh, 0),        tid);
  stage_half(Ag + 128 * KK,  0, ABUF(sh, 0) + 8192, tid);
#pragma unroll
  for (int n = 0; n < 4; ++n)
    bE[n] = *(const i32x4*)(Bg + (size_t)n * (16 * KK));
  stage_half(Ag,            64, ABUF(sh, 1),        tid);
  stage_half(Ag + 128 * KK, 64, ABUF(sh, 1) + 8192, tid);
  WAITVM(6);  // drains A(0); queue = {B(0):4, A(1):2} = steady invariant
  FENCE; BAR;
  // prefetch afr0(0)
#pragma unroll
  for (int m = 0; m < 4; ++m)
    afr0[m] = ldsfrag(ABUF(sh, 0), wr * 128 + m * 16 + lr, hi);

  // ---- main loop: unrolled x2 so bC/bN alternate with static names
  for (int tt = 0; tt < 31; ++tt) {
    do_tile<0>(tt * 2,     acc, Ag, Bg, sh, tid, lr, hi, wr, afr0, afr1, bE, bO);
    do_tile<0>(tt * 2 + 1, acc, Ag, Bg, sh, tid, lr, hi, wr, afr0, afr1, bO, bE);
  }
  do_tile<1>(62, acc, Ag, Bg, sh, tid, lr, hi, wr, afr0, afr1, bE, bO);
  do_tile<2>(63, acc, Ag, Bg, sh, tid, lr, hi, wr, afr0, afr1, bO, bE);

  // ---- epilogue: dequant (dA[row] * scales[col]) + bias, fp32 store
  // C/D layout: col = lane&15, row = (lane>>4)*4 + reg
  const int colb = bn * 256 + wc * 64 + lr;
  const int rowb0 = bm * 256 + wr * 128 + (hi << 2);
#pragma unroll
  for (int m = 0; m < 8; ++m) {
    const int row = rowb0 + m * 16;
    const float da0 = dA[row], da1 = dA[row + 1], da2 = dA[row + 2], da3 = dA[row + 3];
#pragma unroll
    for (int n = 0; n < 4; ++n) {
      const int col = colb + n * 16;
      const float sc = scales[col];
      const float bi = bias[col];
      out[(size_t)(row + 0) * NN + col] = (float)acc[m][n][0] * (da0 * sc) + bi;
      out[(size_t)(row + 1) * NN + col] = (float)acc[m][n][1] * (da1 * sc) + bi;
      out[(size_t)(row + 2) * NN + col] = (float)acc[m][n][2] * (da2 * sc) + bi;
      out[(size_t)(row + 3) * NN + col] = (float)acc[m][n][3] * (da3 * sc) + bi;
    }
  }
}

// ---- fallback (ws too small): correct but slow -----------------------------
__global__ __launch_bounds__(256) void fb_k(const float* __restrict__ A,
                                            const int* __restrict__ W,
                                            const float* __restrict__ scales,
                                            const float* __restrict__ bias,
                                            float* __restrict__ out) {
  __shared__ float Arow[KK];
  const int m = blockIdx.y;
  const int n0 = blockIdx.x * 256;
  const int tid = threadIdx.x;
  for (int k = tid; k < KK; k += 256) Arow[k] = A[(size_t)m * KK + k];
  __syncthreads();
  const int n = n0 + tid;
  float acc = 0.f;
  const int* wrp = W + (size_t)n * KK;
  for (int k = 0; k < KK; ++k) acc += Arow[k] * (float)wrp[k];
  out[(size_t)m * NN + n] = acc * scales[n] + bias[n];
}

extern "C" void kernel_launch(void* const* d_in, const int* in_sizes, int n_in,
                              void* d_out, int out_size, void* d_ws, size_t ws_size,
                              hipStream_t stream) {
  const float* input = (const float*)d_in[0];
  const int* w8 = (const int*)d_in[1];
  const float* scales = (const float*)d_in[2];
  const float* bias = (const float*)d_in[3];
  float* out = (float*)d_out;

  const size_t nelem = (size_t)NN * KK;                    // 16,777,216
  const size_t need = 2 * nelem + MM * sizeof(float);      // 32 MiB + 16 KiB

  if (ws_size >= need) {
    u8* Wq = (u8*)d_ws;
    u8* Aq = Wq + nelem;
    float* dA = (float*)(Aq + nelem);
    cvt_k<<<8192, 256, 0, stream>>>(w8, Wq, input, Aq, dA);
    gemm_k<<<256, 512, 0, stream>>>(Aq, Wq, dA, scales, bias, out);
  } else {
    dim3 grid(NN / 256, MM);
    fb_k<<<grid, 256, 0, stream>>>(input, w8, scales, bias, out);
  }
}

// Round 15
// 90.118 us; speedup vs baseline: 1.3666x; 1.3666x over previous
//
#include <hip/hip_runtime.h>
#include <hip/hip_bf16.h>

typedef unsigned short u16;
typedef unsigned int u32;
typedef unsigned char u8;
typedef __attribute__((ext_vector_type(4))) int i32x4;

#define MM 4096
#define NN 4096
#define KK 4096   // K in elements == bytes for int8

#define BAR __builtin_amdgcn_s_barrier()
#define FENCE asm volatile("" ::: "memory")
#define WAITVM(n) asm volatile("s_waitcnt vmcnt(" #n ")" ::: "memory")

// LDS (bytes), BK=128: A0 @0 (32K), B0 @32768, A1 @65536, B1 @98304 = 128 KiB
#define ABUF(sh, b) ((sh) + (b) * 65536)
#define BBUF(sh, b) ((sh) + 32768 + (b) * 65536)

// ---- merged conversion pass -----------------------------------------------
__global__ __launch_bounds__(256) void cvt_k(const int* __restrict__ w,
                                             u8* __restrict__ ow,
                                             const float* __restrict__ x,
                                             u8* __restrict__ oa,
                                             float* __restrict__ dA) {
  const int bid = blockIdx.x;
  const int t = threadIdx.x;
  if (bid < 4096) {
    int i = bid * 256 + t;
    const int4* w4 = (const int4*)w + (size_t)i * 4;
    i32x4 r;
#pragma unroll
    for (int j = 0; j < 4; ++j) {
      int4 v = w4[j];
      r[j] = (v.x & 255) | ((v.y & 255) << 8) | ((v.z & 255) << 16) |
             ((u32)(v.w & 255) << 24);
    }
    *(i32x4*)(ow + (size_t)i * 16) = r;
  } else {
    const int row = bid - 4096;
    const float4* xr = (const float4*)(x + (size_t)row * KK);
    float4 v[4];
    float mx = 0.f;
#pragma unroll
    for (int j = 0; j < 4; ++j) {
      v[j] = xr[t + j * 256];
      mx = fmaxf(mx, fmaxf(fmaxf(fabsf(v[j].x), fabsf(v[j].y)),
                           fmaxf(fabsf(v[j].z), fabsf(v[j].w))));
    }
#pragma unroll
    for (int off = 32; off; off >>= 1) mx = fmaxf(mx, __shfl_down(mx, off));
    __shared__ float sm[4];
    if ((t & 63) == 0) sm[t >> 6] = mx;
    __syncthreads();
    mx = fmaxf(fmaxf(sm[0], sm[1]), fmaxf(sm[2], sm[3]));
    mx = fmaxf(mx, 1e-20f);
    const float inv = 127.0f / mx;
    if (t == 0) dA[row] = mx / 127.0f;
    u32* orow = (u32*)(oa + (size_t)row * KK);
#pragma unroll
    for (int j = 0; j < 4; ++j) {
      int qx = (int)rintf(v[j].x * inv), qy = (int)rintf(v[j].y * inv);
      int qz = (int)rintf(v[j].z * inv), qw = (int)rintf(v[j].w * inv);
      orow[t + j * 256] =
          (qx & 255) | ((qy & 255) << 8) | ((qz & 255) << 16) | ((u32)(qw & 255) << 24);
    }
  }
}

// ---- async global->LDS, width 16 ------------------------------------------
__device__ __forceinline__ void gload16(const u8* g, u8* l) {
  __builtin_amdgcn_global_load_lds(
      (const __attribute__((address_space(1))) void*)g,
      (__attribute__((address_space(3))) void*)l, 16, 0, 0);
}

// One pass of staging a 256x128B operand tile (32 KiB = 4 passes x 512 thr).
// LDS dest linear; T2 swizzle via permuted global source chunk (8 chunks/row).
__device__ __forceinline__ void stage_q(const u8* __restrict__ gRowBase,
                                        int k0, u8* lds, int tid, int pass) {
  int p = pass * 512 + tid;                // 16B chunk, 0..2047
  int row = p >> 3;                        // 8 chunks per 128B row
  int c = (p & 7) ^ (row & 7);             // involutive swizzle
  gload16(gRowBase + (size_t)row * KK + k0 + c * 16, lds + p * 16);
}

// Swizzled read of one 16B i8 fragment at logical (row r, 16B-chunk q in 0..7).
// bank = 4*((q^r)&7): 16 lr-rows -> 8 slots = 2-way aliasing (free, m136).
__device__ __forceinline__ i32x4 ldsfrag(const u8* base, int r, int q) {
  return *(const i32x4*)(base + r * 128 + (((q ^ r) & 7) << 4));
}

#define MFMAI8(a, b, c) __builtin_amdgcn_mfma_i32_16x16x64_i8(a, b, c, 0, 0, 0)

// ---- 256x256 tile, BK=128, 8 regions/tile, ONE barrier + ONE vmcnt/tile ----
// Groups (8 MFMA each): (mh,kh,n-pair); kh0+kh1 accumulate into same acc.
// Reads one region ahead; stages (t+1) at R1/R2; WAITVM(0)+BAR at R6-end
// (loads issued ~4 regions (~1300cyc) prior > HBM latency; bar publishes
// (t+1) data AND closes the (t-1)-buffer read window for next tile's stage).
// Frag registers cycle with last-use-before-overwrite verified per region.
template <bool LAST>  // LAST = t==31
__device__ __forceinline__ void do_tile(
    int t, i32x4 (&acc)[8][4], const u8* Ag, const u8* Wg, u8* sh,
    int tid, int lr, int hi, int wr, int wc,
    i32x4 (&afr0)[4], i32x4 (&afr1)[4], i32x4 (&b01)[2], i32x4 (&b23)[2]) {
  const int b = t & 1;
  u8* Acur = ABUF(sh, b);
  u8* Anxt = ABUF(sh, b ^ 1);
  u8* Bcur = BBUF(sh, b);
  u8* Bnxt = BBUF(sh, b ^ 1);

  // ---- R1: read b23 = B(kh0,n23); stage B(t+1); MFMA (mh0,kh0,n01)
#pragma unroll
  for (int n = 0; n < 2; ++n)
    b23[n] = ldsfrag(Bcur, wc * 64 + (2 + n) * 16 + lr, hi);
  if (!LAST) {
#pragma unroll
    for (int ps = 0; ps < 4; ++ps) stage_q(Wg, (t + 1) * 128, Bnxt, tid, ps);
  }
  __builtin_amdgcn_s_setprio(1);
#pragma unroll
  for (int m = 0; m < 4; ++m)
#pragma unroll
    for (int n = 0; n < 2; ++n)
      acc[m][n] = MFMAI8(afr0[m], b01[n], acc[m][n]);
  __builtin_amdgcn_s_setprio(0);

  // ---- R2: read afr1 = A(mh1,kh0); stage A(t+1); MFMA (mh0,kh0,n23)
#pragma unroll
  for (int m = 0; m < 4; ++m)
    afr1[m] = ldsfrag(Acur, wr * 128 + 64 + m * 16 + lr, hi);
  if (!LAST) {
#pragma unroll
    for (int ps = 0; ps < 4; ++ps) stage_q(Ag, (t + 1) * 128, Anxt, tid, ps);
  }
  __builtin_amdgcn_s_setprio(1);
#pragma unroll
  for (int m = 0; m < 4; ++m)
#pragma unroll
    for (int n = 0; n < 2; ++n)
      acc[m][2 + n] = MFMAI8(afr0[m], b23[n], acc[m][2 + n]);
  __builtin_amdgcn_s_setprio(0);

  // ---- R3: read afr0 = A(mh0,kh1) [overwrite]; MFMA (mh1,kh0,n01)
#pragma unroll
  for (int m = 0; m < 4; ++m)
    afr0[m] = ldsfrag(Acur, wr * 128 + m * 16 + lr, 4 + hi);
  __builtin_amdgcn_s_setprio(1);
#pragma unroll
  for (int m = 0; m < 4; ++m)
#pragma unroll
    for (int n = 0; n < 2; ++n)
      acc[4 + m][n] = MFMAI8(afr1[m], b01[n], acc[4 + m][n]);
  __builtin_amdgcn_s_setprio(0);

  // ---- R4: read b01 = B(kh1,n01) [overwrite]; MFMA (mh1,kh0,n23)
#pragma unroll
  for (int n = 0; n < 2; ++n)
    b01[n] = ldsfrag(Bcur, wc * 64 + n * 16 + lr, 4 + hi);
  __builtin_amdgcn_s_setprio(1);
#pragma unroll
  for (int m = 0; m < 4; ++m)
#pragma unroll
    for (int n = 0; n < 2; ++n)
      acc[4 + m][2 + n] = MFMAI8(afr1[m], b23[n], acc[4 + m][2 + n]);
  __builtin_amdgcn_s_setprio(0);

  // ---- R5: read b23 = B(kh1,n23) [overwrite]; MFMA (mh0,kh1,n01)
#pragma unroll
  for (int n = 0; n < 2; ++n)
    b23[n] = ldsfrag(Bcur, wc * 64 + (2 + n) * 16 + lr, 4 + hi);
  __builtin_amdgcn_s_setprio(1);
#pragma unroll
  for (int m = 0; m < 4; ++m)
#pragma unroll
    for (int n = 0; n < 2; ++n)
      acc[m][n] = MFMAI8(afr0[m], b01[n], acc[m][n]);
  __builtin_amdgcn_s_setprio(0);

  // ---- R6: read afr1 = A(mh1,kh1) [overwrite]; MFMA (mh0,kh1,n23);
  //          WAITVM(0) (tile t+1 landed) + the tile's ONE barrier
#pragma unroll
  for (int m = 0; m < 4; ++m)
    afr1[m] = ldsfrag(Acur, wr * 128 + 64 + m * 16 + lr, 4 + hi);
  __builtin_amdgcn_s_setprio(1);
#pragma unroll
  for (int m = 0; m < 4; ++m)
#pragma unroll
    for (int n = 0; n < 2; ++n)
      acc[m][2 + n] = MFMAI8(afr0[m], b23[n], acc[m][2 + n]);
  __builtin_amdgcn_s_setprio(0);
  if (!LAST) {
    WAITVM(0);
    FENCE; BAR;
  }

  // ---- R7: read afr0 = A(mh0,kh0)(t+1); MFMA (mh1,kh1,n01)
  if (!LAST) {
#pragma unroll
    for (int m = 0; m < 4; ++m)
      afr0[m] = ldsfrag(Anxt, wr * 128 + m * 16 + lr, hi);
  }
  __builtin_amdgcn_s_setprio(1);
#pragma unroll
  for (int m = 0; m < 4; ++m)
#pragma unroll
    for (int n = 0; n < 2; ++n)
      acc[4 + m][n] = MFMAI8(afr1[m], b01[n], acc[4 + m][n]);
  __builtin_amdgcn_s_setprio(0);

  // ---- R8: read b01 = B(kh0,n01)(t+1); MFMA (mh1,kh1,n23)
  if (!LAST) {
#pragma unroll
    for (int n = 0; n < 2; ++n)
      b01[n] = ldsfrag(Bnxt, wc * 64 + n * 16 + lr, hi);
  }
  __builtin_amdgcn_s_setprio(1);
#pragma unroll
  for (int m = 0; m < 4; ++m)
#pragma unroll
    for (int n = 0; n < 2; ++n)
      acc[4 + m][2 + n] = MFMAI8(afr1[m], b23[n], acc[4 + m][2 + n]);
  __builtin_amdgcn_s_setprio(0);
}

__global__ __launch_bounds__(512, 2) void gemm_k(const u8* __restrict__ A,
                                                 const u8* __restrict__ W,
                                                 const float* __restrict__ dA,
                                                 const float* __restrict__ scales,
                                                 const float* __restrict__ bias,
                                                 float* __restrict__ out) {
  __shared__ u8 sh[131072];  // 128 KiB

  // T1: XCD-aware swizzle (nwg = 256)
  const int cpx = gridDim.x >> 3;
  const int wg = (blockIdx.x & 7) * cpx + (blockIdx.x >> 3);
  const int bm = wg >> 4;
  const int bn = wg & 15;

  const int tid = threadIdx.x;
  const int lane = tid & 63;
  const int lr = lane & 15;
  const int hi = lane >> 4;
  const int wid = tid >> 6;
  const int wr = wid >> 2;  // 2 (M) x 4 (N) wave grid; wave tile 128x64
  const int wc = wid & 3;

  i32x4 acc[8][4] = {};
  i32x4 afr0[4], afr1[4], b01[2], b23[2];

  const u8* Ag = A + (size_t)bm * 256 * KK;
  const u8* Wg = W + (size_t)bn * 256 * KK;

  // ---- prologue: stage tile0 only; t=0's R1/R2 stage tile1
#pragma unroll
  for (int ps = 0; ps < 4; ++ps) stage_q(Wg, 0, BBUF(sh, 0), tid, ps);
#pragma unroll
  for (int ps = 0; ps < 4; ++ps) stage_q(Ag, 0, ABUF(sh, 0), tid, ps);
  WAITVM(0);
  FENCE; BAR;
  // prefetch operands for R1(0): afr0 = A(mh0,kh0), b01 = B(kh0,n01)
#pragma unroll
  for (int m = 0; m < 4; ++m)
    afr0[m] = ldsfrag(ABUF(sh, 0), wr * 128 + m * 16 + lr, hi);
#pragma unroll
  for (int n = 0; n < 2; ++n)
    b01[n] = ldsfrag(BBUF(sh, 0), wc * 64 + n * 16 + lr, hi);

  for (int t = 0; t < 31; ++t)
    do_tile<false>(t, acc, Ag, Wg, sh, tid, lr, hi, wr, wc, afr0, afr1, b01, b23);
  do_tile<true>(31, acc, Ag, Wg, sh, tid, lr, hi, wr, wc, afr0, afr1, b01, b23);

  // ---- epilogue: dequant (dA[row] * scales[col]) + bias, fp32 store
  // C/D layout: col = lane&15, row = (lane>>4)*4 + reg
  const int colb = bn * 256 + wc * 64 + lr;
  const int rowb0 = bm * 256 + wr * 128 + (hi << 2);
#pragma unroll
  for (int m = 0; m < 8; ++m) {
    const int row = rowb0 + m * 16;
    const float da0 = dA[row], da1 = dA[row + 1], da2 = dA[row + 2], da3 = dA[row + 3];
#pragma unroll
    for (int n = 0; n < 4; ++n) {
      const int col = colb + n * 16;
      const float sc = scales[col];
      const float bi = bias[col];
      out[(size_t)(row + 0) * NN + col] = (float)acc[m][n][0] * (da0 * sc) + bi;
      out[(size_t)(row + 1) * NN + col] = (float)acc[m][n][1] * (da1 * sc) + bi;
      out[(size_t)(row + 2) * NN + col] = (float)acc[m][n][2] * (da2 * sc) + bi;
      out[(size_t)(row + 3) * NN + col] = (float)acc[m][n][3] * (da3 * sc) + bi;
    }
  }
}

// ---- fallback (ws too small): correct but slow -----------------------------
__global__ __launch_bounds__(256) void fb_k(const float* __restrict__ A,
                                            const int* __restrict__ W,
                                            const float* __restrict__ scales,
                                            const float* __restrict__ bias,
                                            float* __restrict__ out) {
  __shared__ float Arow[KK];
  const int m = blockIdx.y;
  const int n0 = blockIdx.x * 256;
  const int tid = threadIdx.x;
  for (int k = tid; k < KK; k += 256) Arow[k] = A[(size_t)m * KK + k];
  __syncthreads();
  const int n = n0 + tid;
  float acc = 0.f;
  const int* wrp = W + (size_t)n * KK;
  for (int k = 0; k < KK; ++k) acc += Arow[k] * (float)wrp[k];
  out[(size_t)m * NN + n] = acc * scales[n] + bias[n];
}

extern "C" void kernel_launch(void* const* d_in, const int* in_sizes, int n_in,
                              void* d_out, int out_size, void* d_ws, size_t ws_size,
                              hipStream_t stream) {
  const float* input = (const float*)d_in[0];
  const int* w8 = (const int*)d_in[1];
  const float* scales = (const float*)d_in[2];
  const float* bias = (const float*)d_in[3];
  float* out = (float*)d_out;

  const size_t nelem = (size_t)NN * KK;                    // 16,777,216
  const size_t need = 2 * nelem + MM * sizeof(float);      // 32 MiB + 16 KiB

  if (ws_size >= need) {
    u8* Wq = (u8*)d_ws;
    u8* Aq = Wq + nelem;
    float* dA = (float*)(Aq + nelem);
    cvt_k<<<8192, 256, 0, stream>>>(w8, Wq, input, Aq, dA);
    gemm_k<<<256, 512, 0, stream>>>(Aq, Wq, dA, scales, bias, out);
  } else {
    dim3 grid(NN / 256, MM);
    fb_k<<<grid, 256, 0, stream>>>(input, w8, scales, bias, out);
  }
}